// Round 1
// baseline (1758.151 us; speedup 1.0000x reference)
//
#include <hip/hip_runtime.h>
#include <hip/hip_bf16.h>

// RNN car-following model: 8192 vehicles x 1000 steps, LSTM(20) + dense heads.
// Block = 16 vehicles, 320 threads (5 waves). 512 blocks.
// Wave w computes z-columns [16w,16w+16) of the 32->80 LSTM affine via one
// mfma_f32_16x16x32_bf16; gate nonlinearities are distributed one (veh,unit)
// pair per thread; x/lc/acc head matmuls are done by wave 0 via two more MFMAs.

typedef __attribute__((ext_vector_type(8))) short short8;
typedef __attribute__((ext_vector_type(4))) short short4v;
typedef __attribute__((ext_vector_type(4))) float float4v;

__device__ __forceinline__ short f2b(float f) {
    // float -> bf16 (RNE), raw bits in a short
    unsigned u = __float_as_uint(f);
    u += 0x7fffu + ((u >> 16) & 1u);
    return (short)(u >> 16);
}

__device__ __forceinline__ float fast_exp2(float x) {
#if __has_builtin(__builtin_amdgcn_exp2f)
    return __builtin_amdgcn_exp2f(x);
#else
    return exp2f(x);
#endif
}

__device__ __forceinline__ float fast_rcp(float x) {
#if __has_builtin(__builtin_amdgcn_rcpf)
    return __builtin_amdgcn_rcpf(x);
#else
    return 1.0f / x;
#endif
}

#define L2E 1.44269504088896340736f

__global__ void __launch_bounds__(320) rnncf_kernel(
    const float* __restrict__ inp,        // (8192,1000,12)
    const float* __restrict__ init_state, // (8192,2)
    const float* __restrict__ h0g,        // (8192,20)
    const float* __restrict__ c0g,        // (8192,20)
    const float* __restrict__ Wk,         // (12,80)
    const float* __restrict__ Wr,         // (20,80)
    const float* __restrict__ bz_g,       // (80,)
    const float* __restrict__ W2,         // (20,10)
    const float* __restrict__ b2_g,       // (10,)
    const float* __restrict__ Wlc,        // (10,3)
    const float* __restrict__ blc,        // (3,)
    const float* __restrict__ Wd1,        // (10,1)
    const float* __restrict__ bd1,        // (1,)
    float* __restrict__ out)
{
    __shared__ short h_lds[16 * 32];   // h as bf16, rows m, k-padded to 32 (pad=0)
    __shared__ short x_lds[16 * 32];   // x as bf16, rows m, k-padded to 32 (pad=0)
    __shared__ float z_lds[80 * 20];   // z[n][m], row stride 20 floats
    __shared__ float pos_lds[16];

    const int tid = threadIdx.x;
    const int w   = tid >> 6;     // wave 0..4
    const int l   = tid & 63;
    const int q   = l >> 4;       // quad 0..3
    const int col = l & 15;
    const int v0  = blockIdx.x * 16;

    float* out_pos = out;                 // 8192*1000
    float* out_lc  = out + 8192000;       // 8192*1000*3
    float* out_spd = out + 32768000;      // 8192
    float* out_h   = out + 32776192;      // 8192*20
    float* out_c   = out + 32940032;      // 8192*20

    // ---- preload B fragments (B[k=8q+j][n=col]) ----
    short8 b1, b2, b3;
    {
        int n = 16 * w + col;
#pragma unroll
        for (int j = 0; j < 8; ++j) {
            int k = 8 * q + j;
            float v = (k < 12) ? Wk[k * 80 + n] : Wr[(k - 12) * 80 + n];
            b1[j] = f2b(v);
            float v2 = (k < 20 && col < 10) ? W2[k * 10 + col] : 0.0f;
            b2[j] = f2b(v2);
            float v3 = 0.0f;
            if (k < 10) {
                if (col < 3) v3 = Wlc[k * 3 + col];
                else if (col == 3) v3 = Wd1[k];
            }
            b3[j] = f2b(v3);
        }
    }
    const float biasz = bz_g[16 * w + col];
    const float bias2 = (col < 10) ? b2_g[col] : 0.0f;
    const float bias3 = (col < 3) ? blc[col] : ((col == 3) ? bd1[0] : 0.0f);

    // ---- gate-thread mapping: one (vehicle, unit) per thread ----
    const int gm = tid & 15;      // vehicle 0..15
    const int gu = tid >> 4;      // unit 0..19
    float c_state = c0g[(size_t)(v0 + gm) * 20 + gu];
    float h_last  = 0.0f;

    // ---- LDS init ----
    h_lds[gm * 32 + gu] = f2b(h0g[(size_t)(v0 + gm) * 20 + gu]);
    for (int idx = tid; idx < 16 * 12; idx += 320) {        // h pad k=20..32
        h_lds[(idx & 15) * 32 + 20 + (idx >> 4)] = 0;
    }
    for (int idx = tid; idx < 16 * 22; idx += 320) {        // x pad k=10..32
        x_lds[(idx & 15) * 32 + 10 + (idx >> 4)] = 0;
    }

    float pos_r[4] = {0.f, 0.f, 0.f, 0.f};
    float spd_r[4] = {0.f, 0.f, 0.f, 0.f};
    if (w == 0 && col == 3) {
#pragma unroll
        for (int r = 0; r < 4; ++r) {
            pos_r[r] = init_state[(size_t)(v0 + 4 * q + r) * 2 + 0];
            spd_r[r] = init_state[(size_t)(v0 + 4 * q + r) * 2 + 1];
            pos_lds[4 * q + r] = pos_r[r];
        }
    }
    __syncthreads();

    for (int t = 0; t < 1000; ++t) {
        // ================= Phase A: z = [cur|h] @ W1 + bias (all 5 waves) ====
        short8 a1;
        {
            int m = col;  // A row = vehicle
            const float* ip = inp + ((size_t)(v0 + m) * 1000 + t) * 12;
            if (q == 0) {
                float4v f0 = *(const float4v*)ip;        // lead0..2, fol0
                float4v f1 = *(const float4v*)(ip + 4);  // fol1, fol2, spd0, spd1
                float p = pos_lds[m];
                a1[0] = f2b((f0[0] - p) * 0.01f);
                a1[1] = f2b((f0[1] - p) * 0.01f);
                a1[2] = f2b((f0[2] - p) * 0.01f);
                a1[3] = f2b((p - f0[3]) * 0.01f);
                a1[4] = f2b((p - f1[0]) * 0.01f);
                a1[5] = f2b((p - f1[1]) * 0.01f);
                a1[6] = f2b(f1[2] * 0.025f);
                a1[7] = f2b(f1[3] * 0.025f);
            } else if (q == 1) {
                float4v f2 = *(const float4v*)(ip + 8);  // spd2..spd5
                a1[0] = f2b(f2[0] * 0.025f);
                a1[1] = f2b(f2[1] * 0.025f);
                a1[2] = f2b(f2[2] * 0.025f);
                a1[3] = f2b(f2[3] * 0.025f);
                short4v hv = *(const short4v*)&h_lds[m * 32 + 0];  // h[0..4)
                a1[4] = hv[0]; a1[5] = hv[1]; a1[6] = hv[2]; a1[7] = hv[3];
            } else {
                int off = (q == 2) ? 4 : 12;  // h[4..12) or h[12..20)
                short4v ha = *(const short4v*)&h_lds[m * 32 + off];
                short4v hb = *(const short4v*)&h_lds[m * 32 + off + 4];
                a1[0] = ha[0]; a1[1] = ha[1]; a1[2] = ha[2]; a1[3] = ha[3];
                a1[4] = hb[0]; a1[5] = hb[1]; a1[6] = hb[2]; a1[7] = hb[3];
            }
        }
        float4v accz = {biasz, biasz, biasz, biasz};
        accz = __builtin_amdgcn_mfma_f32_16x16x32_bf16(a1, b1, accz, 0, 0, 0);
        // D: lane holds z[n = 16w+col][m = 4q+r]; write 4 consecutive m
        *(float4v*)&z_lds[(16 * w + col) * 20 + 4 * q] = accz;
        __syncthreads();

        // ================= Phase B: LSTM gates (one (m,u) pair/thread) =======
        {
            float zi = z_lds[gu * 20 + gm];
            float zf = z_lds[(gu + 20) * 20 + gm];
            float zg = z_lds[(gu + 40) * 20 + gm];
            float zo = z_lds[(gu + 60) * 20 + gm];
            zi = fminf(fmaxf(zi, -20.f), 20.f);
            zf = fminf(fmaxf(zf, -20.f), 20.f);
            zg = fminf(fmaxf(zg, -20.f), 20.f);
            zo = fminf(fmaxf(zo, -20.f), 20.f);
            // sig(f)*c + sig(i)*tanh(g) with a single fused reciprocal
            float A = fast_exp2(-L2E * zi);         // e^{-zi}
            float B = fast_exp2(-L2E * zf);         // e^{-zf}
            float C = fast_exp2(2.0f * L2E * zg);   // e^{2 zg}
            float pA = 1.0f + A, pB = 1.0f + B, pC = C + 1.0f, mC = C - 1.0f;
            float t1 = pA * pC;
            float R1 = fast_rcp(t1 * pB);
            float cn = (c_state * t1 + mC * pB) * R1;
            c_state = cn;
            // h = sig(o) * tanh(c)
            float cc = fminf(fmaxf(cn, -20.f), 20.f);
            float D  = fast_exp2(-L2E * zo);        // e^{-zo}
            float E  = fast_exp2(2.0f * L2E * cc);  // e^{2 c}
            float h  = (E - 1.0f) * fast_rcp((1.0f + D) * (E + 1.0f));
            h_last = h;
            h_lds[gm * 32 + gu] = f2b(h);
        }
        __syncthreads();

        // ================= Phase C: x = relu(h @ W2 + b2) (wave 0) ===========
        if (w == 0) {
            short8 a2 = *(const short8*)&h_lds[col * 32 + 8 * q];
            float4v accx = {bias2, bias2, bias2, bias2};
            accx = __builtin_amdgcn_mfma_f32_16x16x32_bf16(a2, b2, accx, 0, 0, 0);
            if (col < 10) {
#pragma unroll
                for (int r = 0; r < 4; ++r)
                    x_lds[(4 * q + r) * 32 + col] = f2b(fmaxf(accx[r], 0.0f));
            }
        }
        __syncthreads();

        // ================= Phase D: [lc|acc] = x @ [Wlc|Wd1] (wave 0) ========
        if (w == 0) {
            short8 a3 = *(const short8*)&x_lds[col * 32 + 8 * q];
            float4v accf = {bias3, bias3, bias3, bias3};
            accf = __builtin_amdgcn_mfma_f32_16x16x32_bf16(a3, b3, accf, 0, 0, 0);
            if (col < 3) {
#pragma unroll
                for (int r = 0; r < 4; ++r)
                    out_lc[(size_t)(v0 + 4 * q + r) * 3000 + t * 3 + col] = accf[r];
            } else if (col == 3) {
#pragma unroll
                for (int r = 0; r < 4; ++r) {
                    float acc = 10.0f * accf[r] - 6.0f;   // (MAXA-MINA)*raw + MINA
                    pos_r[r] += 0.1f * spd_r[r];          // pos uses old spd
                    spd_r[r] += 0.1f * acc;
                    out_pos[(size_t)(v0 + 4 * q + r) * 1000 + t] = pos_r[r];
                }
                float4v pv = {pos_r[0], pos_r[1], pos_r[2], pos_r[3]};
                *(float4v*)&pos_lds[4 * q] = pv;
            }
        }
        __syncthreads();
    }

    // ---- final outputs ----
    if (w == 0 && col == 3) {
#pragma unroll
        for (int r = 0; r < 4; ++r)
            out_spd[v0 + 4 * q + r] = spd_r[r];
    }
    out_h[(size_t)(v0 + gm) * 20 + gu] = h_last;
    out_c[(size_t)(v0 + gm) * 20 + gu] = c_state;
}

extern "C" void kernel_launch(void* const* d_in, const int* in_sizes, int n_in,
                              void* d_out, int out_size, void* d_ws, size_t ws_size,
                              hipStream_t stream) {
    rnncf_kernel<<<512, 320, 0, stream>>>(
        (const float*)d_in[0],  (const float*)d_in[1],  (const float*)d_in[2],
        (const float*)d_in[3],  (const float*)d_in[4],  (const float*)d_in[5],
        (const float*)d_in[6],  (const float*)d_in[7],  (const float*)d_in[8],
        (const float*)d_in[9],  (const float*)d_in[10], (const float*)d_in[11],
        (const float*)d_in[12], (float*)d_out);
}

// Round 2
// 1507.441 us; speedup vs baseline: 1.1663x; 1.1663x over previous
//
#include <hip/hip_runtime.h>
#include <hip/hip_bf16.h>

// One wave owns 16 vehicles for all 1000 steps. No __syncthreads anywhere.
// MFMA operand swap: A = W^T (rows = interleaved z-cols n' = 4u+gate),
// B = [cur|h]^T (cols = vehicles) => D gives lane(col=m, quad=q) the 4 gate
// pre-activations of unit u=4p+q in its 4 accumulator regs. Gate scale
// (+-log2e / 2log2e) and bias folded into weights / C-operand.
// Block = 128 (2 independent waves), grid = 256 => 1 block/CU.

typedef __attribute__((ext_vector_type(8))) short short8;
typedef __attribute__((ext_vector_type(4))) short short4v;
typedef __attribute__((ext_vector_type(4))) float float4v;
typedef __attribute__((ext_vector_type(2))) float float2v;

__device__ __forceinline__ short f2b(float f) {
    unsigned u = __float_as_uint(f);
    u += 0x7fffu + ((u >> 16) & 1u);
    return (short)(u >> 16);
}

__device__ __forceinline__ float fast_exp2(float x) {
#if __has_builtin(__builtin_amdgcn_exp2f)
    return __builtin_amdgcn_exp2f(x);
#else
    return exp2f(x);
#endif
}
__device__ __forceinline__ float fast_rcp(float x) {
#if __has_builtin(__builtin_amdgcn_rcpf)
    return __builtin_amdgcn_rcpf(x);
#else
    return 1.0f / x;
#endif
}

#define L2E 1.44269504088896340736f

__global__ void __launch_bounds__(128) rnncf_kernel(
    const float* __restrict__ inp,        // (8192,1000,12)
    const float* __restrict__ init_state, // (8192,2)
    const float* __restrict__ h0g,        // (8192,20)
    const float* __restrict__ c0g,        // (8192,20)
    const float* __restrict__ Wk,         // (12,80)
    const float* __restrict__ Wr,         // (20,80)
    const float* __restrict__ bz_g,       // (80,)
    const float* __restrict__ W2,         // (20,10)
    const float* __restrict__ b2_g,       // (10,)
    const float* __restrict__ Wlc,        // (10,3)
    const float* __restrict__ blc,        // (3,)
    const float* __restrict__ Wd1,        // (10,1)
    const float* __restrict__ bd1,        // (1,)
    float* __restrict__ out)
{
    // per-wave LDS slices (2 waves/block), h rows padded to 36 shorts (72 B:
    // 18m mod 32 distinct for m=0..15 -> conflict-free b64 fragment reads)
    __shared__ short h_lds[2][16 * 36];
    __shared__ float x_lds[2][16 * 12];
    __shared__ float pos_lds[2][16];

    const int tid = threadIdx.x;
    const int wv  = tid >> 6;
    const int l   = tid & 63;
    const int q   = l >> 4;      // quad 0..3
    const int col = l & 15;
    const int v0  = (blockIdx.x * 2 + wv) * 16;

    short* hl = h_lds[wv];
    float* xl = x_lds[wv];
    float* pl = pos_lds[wv];

    float* out_pos = out;                 // 8192*1000
    float* out_lc  = out + 8192000;       // 8192*1000*3
    float* out_spd = out + 32768000;      // 8192
    float* out_h   = out + 32776192;      // 8192*20
    float* out_c   = out + 32940032;      // 8192*20

    // ---- weight prep: A-fragments of the swapped MFMAs ----
    // z-MFMA p covers absolute rows n' = 16p + col; n' = 4u + g, scale sg[g].
    const float sgt[4] = {-L2E, -L2E, 2.0f * L2E, -L2E};
    const int g  = col & 3;        // gate index of this lane's A-row
    const int cu = col >> 2;
    short8  w1t[5];
    float4v bz1[5];
#pragma unroll
    for (int p = 0; p < 5; ++p) {
        const int n = g * 20 + 4 * p + cu;   // original z column
#pragma unroll
        for (int j = 0; j < 8; ++j) {
            int k = 8 * q + j;
            float wvl = (k < 12) ? Wk[k * 80 + n] : Wr[(k - 12) * 80 + n];
            w1t[p][j] = f2b(wvl * sgt[g]);
        }
#pragma unroll
        for (int r = 0; r < 4; ++r)
            bz1[p][r] = sgt[r] * bz_g[r * 20 + 4 * p + q];  // D-row 4q+r of block p
    }
    short8 w2t;   // phase-C A-frag: A[n=col][k=u] = W2[u][n]
#pragma unroll
    for (int j = 0; j < 8; ++j) {
        int k = 8 * q + j;
        float v = (col < 10 && k < 20) ? W2[k * 10 + col] : 0.0f;
        w2t[j] = f2b(v);
    }
    float4v bx;
#pragma unroll
    for (int r = 0; r < 4; ++r) { int n = 4 * q + r; bx[r] = (n < 10) ? b2_g[n] : 0.0f; }

    // phase-D: lane l = 4*dm + dj computes output dj of vehicle dm
    const int dm = l >> 2, dj = l & 3;
    float wd[10], bd;
#pragma unroll
    for (int n = 0; n < 10; ++n) wd[n] = (dj < 3) ? Wlc[n * 3 + dj] : Wd1[n];
    bd = (dj < 3) ? blc[dj] : bd1[0];

    // ---- state init ----
    float c_st[5], h_keep[5];
#pragma unroll
    for (int p = 0; p < 5; ++p) {
        c_st[p] = c0g[(size_t)(v0 + col) * 20 + 4 * p + q];
        h_keep[p] = 0.0f;
    }
    for (int i = l; i < 16 * 36; i += 64) hl[i] = 0;   // zero incl. pad u=20..35
#pragma unroll
    for (int p = 0; p < 5; ++p)
        hl[col * 36 + 4 * p + q] = f2b(h0g[(size_t)(v0 + col) * 20 + 4 * p + q]);

    float pos = 0.0f, spd = 0.0f;
    if (dj == 3) {
        pos = init_state[(size_t)(v0 + dm) * 2 + 0];
        spd = init_state[(size_t)(v0 + dm) * 2 + 1];
        pl[dm] = pos;
    }

    // ---- input prefetch (t = 0) ----
    const float* ipbase = inp + (size_t)(v0 + col) * 12000;
    float4v inA = {0, 0, 0, 0}, inB = {0, 0, 0, 0}, inC = {0, 0, 0, 0};
    if (q == 0)      { inA = *(const float4v*)(ipbase + 0); inB = *(const float4v*)(ipbase + 4); }
    else if (q == 1) { inC = *(const float4v*)(ipbase + 8); }

    for (int t = 0; t < 1000; ++t) {
        // pos_t for the fragment (read BEFORE the owner's update below)
        float posv = pl[col];

        // owner lanes: pos_{t+1} = pos_t + DT*spd_t (independent of this
        // step's acc) -> written early so next step's read has a full step of slack
        if (dj == 3) {
            pos += 0.1f * spd;
            pl[dm] = pos;
            out_pos[(size_t)(v0 + dm) * 1000 + t] = pos;
        }

        // ---- build B-frag: B[k=8q+j][m=col] = normalized input / h ----
        short8 bfrag;
        if (q == 0) {
            float pp = posv * 0.01f;
            bfrag[0] = f2b(__builtin_fmaf(inA[0],  0.01f, -pp));
            bfrag[1] = f2b(__builtin_fmaf(inA[1],  0.01f, -pp));
            bfrag[2] = f2b(__builtin_fmaf(inA[2],  0.01f, -pp));
            bfrag[3] = f2b(__builtin_fmaf(inA[3], -0.01f,  pp));
            bfrag[4] = f2b(__builtin_fmaf(inB[0], -0.01f,  pp));
            bfrag[5] = f2b(__builtin_fmaf(inB[1], -0.01f,  pp));
            bfrag[6] = f2b(inB[2] * 0.025f);
            bfrag[7] = f2b(inB[3] * 0.025f);
        } else if (q == 1) {
            bfrag[0] = f2b(inC[0] * 0.025f);
            bfrag[1] = f2b(inC[1] * 0.025f);
            bfrag[2] = f2b(inC[2] * 0.025f);
            bfrag[3] = f2b(inC[3] * 0.025f);
            short4v hv = *(const short4v*)&hl[col * 36 + 0];
            bfrag[4] = hv[0]; bfrag[5] = hv[1]; bfrag[6] = hv[2]; bfrag[7] = hv[3];
        } else {
            int off = (q == 2) ? 4 : 12;
            short4v ha = *(const short4v*)&hl[col * 36 + off];
            short4v hb = *(const short4v*)&hl[col * 36 + off + 4];
            bfrag[0] = ha[0]; bfrag[1] = ha[1]; bfrag[2] = ha[2]; bfrag[3] = ha[3];
            bfrag[4] = hb[0]; bfrag[5] = hb[1]; bfrag[6] = hb[2]; bfrag[7] = hb[3];
        }

        // ---- prefetch inputs for t+1 (overlaps with gates) ----
        {
            int tn = (t < 999) ? t + 1 : 999;
            const float* ipn = ipbase + tn * 12;
            if (q == 0)      { inA = *(const float4v*)ipn; inB = *(const float4v*)(ipn + 4); }
            else if (q == 1) { inC = *(const float4v*)(ipn + 8); }
        }

        // ---- z = W1sc^T @ [cur|h]^T : lane gets gates i,f,g,o of u=4p+q ----
        float4v z[5];
#pragma unroll
        for (int p = 0; p < 5; ++p)
            z[p] = __builtin_amdgcn_mfma_f32_16x16x32_bf16(w1t[p], bfrag, bz1[p], 0, 0, 0);

        // ---- gates (z already scaled: exp2 direct) ----
#pragma unroll
        for (int p = 0; p < 5; ++p) {
            float zi = fminf(fmaxf(z[p][0], -29.f), 29.f);
            float zf = fminf(fmaxf(z[p][1], -29.f), 29.f);
            float zg = fminf(fmaxf(z[p][2], -58.f), 58.f);
            float zo = fminf(fmaxf(z[p][3], -29.f), 29.f);
            float eA = fast_exp2(zi);   // e^{-z_i}
            float eB = fast_exp2(zf);   // e^{-z_f}
            float eC = fast_exp2(zg);   // e^{2 z_g}
            float eD = fast_exp2(zo);   // e^{-z_o}
            float pA = 1.0f + eA, pB = 1.0f + eB, pC = eC + 1.0f, mC = eC - 1.0f;
            float t1 = pA * pC;
            float R  = fast_rcp(t1 * pB);
            float cn = (c_st[p] * t1 + mC * pB) * R;   // sig(f)c + sig(i)tanh(g)
            c_st[p] = cn;
            float ec = fminf(fmaxf(cn * (2.0f * L2E), -58.f), 58.f);
            float eE = fast_exp2(ec);
            float h  = (eE - 1.0f) * fast_rcp((1.0f + eD) * (eE + 1.0f));
            h_keep[p] = h;
            hl[col * 36 + 4 * p + q] = f2b(h);
        }

        // ---- phase C: x = relu(W2^T @ h^T + b2), D rows = x features ----
        short8 hfrag;
        {
            short4v ha = *(const short4v*)&hl[col * 36 + 8 * q];
            short4v hb = *(const short4v*)&hl[col * 36 + 8 * q + 4];
            hfrag[0] = ha[0]; hfrag[1] = ha[1]; hfrag[2] = ha[2]; hfrag[3] = ha[3];
            hfrag[4] = hb[0]; hfrag[5] = hb[1]; hfrag[6] = hb[2]; hfrag[7] = hb[3];
        }
        float4v x4 = __builtin_amdgcn_mfma_f32_16x16x32_bf16(w2t, hfrag, bx, 0, 0, 0);
        if (q < 3) {   // rows 12..15 would spill into the next vehicle's row
            float4v xr;
#pragma unroll
            for (int r = 0; r < 4; ++r) xr[r] = fmaxf(x4[r], 0.0f);
            *(float4v*)&xl[col * 12 + 4 * q] = xr;   // x[m=col][n=4q+r]
        }

        // ---- phase D: 16 veh x 4 outputs = 64 VALU dot-10s ----
        {
            float4v xa = *(const float4v*)&xl[dm * 12 + 0];
            float4v xb = *(const float4v*)&xl[dm * 12 + 4];
            float2v xc = *(const float2v*)&xl[dm * 12 + 8];
            float dot = bd;
            dot = __builtin_fmaf(xa[0], wd[0], dot);
            dot = __builtin_fmaf(xa[1], wd[1], dot);
            dot = __builtin_fmaf(xa[2], wd[2], dot);
            dot = __builtin_fmaf(xa[3], wd[3], dot);
            dot = __builtin_fmaf(xb[0], wd[4], dot);
            dot = __builtin_fmaf(xb[1], wd[5], dot);
            dot = __builtin_fmaf(xb[2], wd[6], dot);
            dot = __builtin_fmaf(xb[3], wd[7], dot);
            dot = __builtin_fmaf(xc[0], wd[8], dot);
            dot = __builtin_fmaf(xc[1], wd[9], dot);
            if (dj < 3) {
                out_lc[(size_t)(v0 + dm) * 3000 + t * 3 + dj] = dot;
            } else {
                float acc = 10.0f * dot - 6.0f;   // (MAXA-MINA)*raw + MINA
                spd += 0.1f * acc;                // pos already advanced above
            }
        }
    }

    // ---- finals ----
    if (dj == 3) out_spd[v0 + dm] = spd;
#pragma unroll
    for (int p = 0; p < 5; ++p) {
        out_h[(size_t)(v0 + col) * 20 + 4 * p + q] = h_keep[p];
        out_c[(size_t)(v0 + col) * 20 + 4 * p + q] = c_st[p];
    }
}

extern "C" void kernel_launch(void* const* d_in, const int* in_sizes, int n_in,
                              void* d_out, int out_size, void* d_ws, size_t ws_size,
                              hipStream_t stream) {
    rnncf_kernel<<<256, 128, 0, stream>>>(
        (const float*)d_in[0],  (const float*)d_in[1],  (const float*)d_in[2],
        (const float*)d_in[3],  (const float*)d_in[4],  (const float*)d_in[5],
        (const float*)d_in[6],  (const float*)d_in[7],  (const float*)d_in[8],
        (const float*)d_in[9],  (const float*)d_in[10], (const float*)d_in[11],
        (const float*)d_in[12], (float*)d_out);
}